// Round 1
// baseline (512.581 us; speedup 1.0000x reference)
//
#include <hip/hip_runtime.h>

typedef __bf16 bf16x8 __attribute__((ext_vector_type(8)));
typedef float  f32x4  __attribute__((ext_vector_type(4)));
typedef unsigned short us8 __attribute__((ext_vector_type(8)));

__device__ __forceinline__ unsigned short f2bf(float f) {
    union { float f; unsigned u; } c; c.f = f;
    unsigned u = c.u;
    u += 0x7FFFu + ((u >> 16) & 1u);   // RNE; inputs are finite
    return (unsigned short)(u >> 16);
}

#define XS   72     // padded ci-stride in LDS (ushorts): 144B -> 2-way bank aliasing (free)
#define NHP  204    // 6*34 halo pixels
#define EPS  66     // epilogue co-half stride (floats), pad 2 -> 2-way only

struct SmemGemm {
    unsigned short x[NHP * XS];   // 29376 B : halo tile [px][ci] bf16
    unsigned short w[128 * XS];   // 18432 B : tap weights [co][ci] bf16
};
union Smem {
    SmemGemm g;                   // 47808 B
    float epi[128 * EPS];         // 33792 B (64-co half of conv outputs)
};

// -------- weight pre-transform: OIHW f32 -> [tap][co][ci] bf16 in d_ws --------
__global__ void __launch_bounds__(256) wxform(const float* __restrict__ W,
                                              unsigned short* __restrict__ wbf) {
    int i = blockIdx.x * 256 + threadIdx.x;       // 73728 = 128*64*9
    if (i < 73728) {
        int co  = i / 576;
        int rem = i % 576;
        int ci  = rem / 9;
        int tap = rem % 9;
        wbf[(tap * 128 + co) * 64 + ci] = f2bf(W[i]);
    }
}

// -------- fused conv3x3 + bias + avgpool2 + sigmoid + per-image sum --------
__global__ void __launch_bounds__(256, 2)
conv_fused(const float* __restrict__ x,
           const unsigned short* __restrict__ wbf,
           const float* __restrict__ bias,
           float* __restrict__ out)
{
    __shared__ __align__(16) Smem sm;
    __shared__ float red[4];

    const int tid  = threadIdx.x;
    const int wave = tid >> 6;        // 0..3 = output row within tile
    const int lane = tid & 63;
    const int lq   = lane >> 4;       // quad 0..3
    const int lm   = lane & 15;

    const int ct = blockIdx.x;        // 0..3   col tile (32 wide)
    const int rt = blockIdx.y;        // 0..31  row tile (4 tall)
    const int n  = blockIdx.z;        // 0..63  image

    const int h0 = rt * 4;
    const int w0 = ct * 32;

    const float* xn = x + (size_t)n * (64u * 128u * 128u);

    // ---- stage x halo: 64ci x 6h x 34w -> LDS [px][ci] bf16 ----
    // task t: px = t%204, ci-group = t/204 (8 ci each). Global reads coalesced
    // along w across lanes; one ds_write_b128 per task.
    for (int it = 0; it < 7; ++it) {
        int t = tid + it * 256;
        if (t < 1632) {
            int px  = t % 204;
            int ci0 = (t / 204) * 8;
            int hh = px / 34, ww = px % 34;
            int h = h0 + hh, w = w0 + ww;
            bool ok = (h < 128) && (w < 128);
            const float* src = xn + (size_t)ci0 * 16384 + h * 128 + w;
            us8 v;
            #pragma unroll
            for (int j = 0; j < 8; ++j) {
                float f = ok ? src[j * 16384] : 0.0f;
                v[j] = f2bf(f);
            }
            *(us8*)&sm.g.x[px * XS + ci0] = v;
        }
    }

    f32x4 acc[2][8];
    #pragma unroll
    for (int mt = 0; mt < 2; ++mt)
        #pragma unroll
        for (int nt = 0; nt < 8; ++nt)
            acc[mt][nt] = (f32x4){0.f, 0.f, 0.f, 0.f};

    // ---- K loop: 9 taps x (K=64 ci as 2 x k32) ----
    for (int tap = 0; tap < 9; ++tap) {
        __syncthreads();  // prior tap done reading lds_w (covers x-stage on tap 0)
        const unsigned short* wt = wbf + tap * 8192;
        #pragma unroll
        for (int it = 0; it < 4; ++it) {           // 1024 tasks exactly
            int t   = tid + it * 256;
            int co  = t >> 3;
            int ci0 = (t & 7) * 8;
            us8 v = *(const us8*)&wt[t * 8];       // contiguous, coalesced
            *(us8*)&sm.g.w[co * XS + ci0] = v;
        }
        __syncthreads();

        const int kh = tap / 3, kw = tap % 3;

        // A frags: A[m=lane&15][k=quad*8+j], m = pixel col within m-tile
        bf16x8 a[2][2];
        #pragma unroll
        for (int mt = 0; mt < 2; ++mt)
            #pragma unroll
            for (int kc = 0; kc < 2; ++kc) {
                int pcol = mt * 16 + lm;
                int hp = (wave + kh) * 34 + pcol + kw;
                a[mt][kc] = *(const bf16x8*)&sm.g.x[hp * XS + kc * 32 + lq * 8];
            }
        #pragma unroll
        for (int nt = 0; nt < 8; ++nt) {
            #pragma unroll
            for (int kc = 0; kc < 2; ++kc) {
                bf16x8 b = *(const bf16x8*)&sm.g.w[(nt * 16 + lm) * XS + kc * 32 + lq * 8];
                acc[0][nt] = __builtin_amdgcn_mfma_f32_16x16x32_bf16(a[0][kc], b, acc[0][nt], 0, 0, 0);
                acc[1][nt] = __builtin_amdgcn_mfma_f32_16x16x32_bf16(a[1][kc], b, acc[1][nt], 0, 0, 0);
            }
        }
    }

    // ---- epilogue: two 64-co halves through LDS ----
    // D layout: row(=pixel col) = quad*4+rr, col(=co) = lane&15
    float part = 0.0f;
    #pragma unroll
    for (int half = 0; half < 2; ++half) {
        __syncthreads();
        #pragma unroll
        for (int mt = 0; mt < 2; ++mt)
            #pragma unroll
            for (int nt4 = 0; nt4 < 4; ++nt4)
                #pragma unroll
                for (int rr = 0; rr < 4; ++rr) {
                    int col  = mt * 16 + lq * 4 + rr;       // pixel col in tile
                    int co_h = nt4 * 16 + lm;               // co within half
                    sm.epi[(wave * 32 + col) * EPS + co_h] = acc[mt][half * 4 + nt4][rr];
                }
        __syncthreads();
        #pragma unroll
        for (int i = 0; i < 8; ++i) {                       // 2048 pool cells / half
            int cell = tid + i * 256;
            int co_h = cell & 63;
            int pc   = (cell >> 6) & 15;
            int pr   = cell >> 10;                          // 0..1
            int ph = (h0 >> 1) + pr;
            int pw = (w0 >> 1) + pc;
            if (ph < 63 && pw < 63) {                       // mask pool boundary
                int r2 = pr * 2, c2 = pc * 2;
                float s = sm.epi[((r2    ) * 32 + c2    ) * EPS + co_h]
                        + sm.epi[((r2    ) * 32 + c2 + 1) * EPS + co_h]
                        + sm.epi[((r2 + 1) * 32 + c2    ) * EPS + co_h]
                        + sm.epi[((r2 + 1) * 32 + c2 + 1) * EPS + co_h];
                float v = 0.25f * s + bias[half * 64 + co_h];
                part += 1.0f / (1.0f + __expf(-v));
            }
        }
    }

    // ---- block reduce -> one atomicAdd per block ----
    #pragma unroll
    for (int off = 32; off > 0; off >>= 1)
        part += __shfl_down(part, off, 64);
    if (lane == 0) red[wave] = part;
    __syncthreads();
    if (tid == 0) atomicAdd(&out[n], red[0] + red[1] + red[2] + red[3]);
}

extern "C" void kernel_launch(void* const* d_in, const int* in_sizes, int n_in,
                              void* d_out, int out_size, void* d_ws, size_t ws_size,
                              hipStream_t stream) {
    const float* x = (const float*)d_in[0];
    const float* W = (const float*)d_in[1];
    const float* b = (const float*)d_in[2];
    float* out = (float*)d_out;
    unsigned short* wbf = (unsigned short*)d_ws;   // 147456 B used

    hipMemsetAsync(d_out, 0, 64 * sizeof(float), stream);
    wxform<<<288, 256, 0, stream>>>(W, wbf);
    conv_fused<<<dim3(4, 32, 64), 256, 0, stream>>>(x, wbf, b, out);
}

// Round 2
// 478.740 us; speedup vs baseline: 1.0707x; 1.0707x over previous
//
#include <hip/hip_runtime.h>

typedef __bf16 bf16x8 __attribute__((ext_vector_type(8)));
typedef float  f32x4  __attribute__((ext_vector_type(4)));
typedef unsigned short us8 __attribute__((ext_vector_type(8)));

__device__ __forceinline__ unsigned short f2bf(float f) {
    union { float f; unsigned u; } c; c.f = f;
    unsigned u = c.u;
    u += 0x7FFFu + ((u >> 16) & 1u);   // RNE; inputs finite
    return (unsigned short)(u >> 16);
}

// async 16B global -> LDS (dest = wave-uniform base + lane*16)
__device__ __forceinline__ void gl2lds16(const void* g, void* l) {
    __builtin_amdgcn_global_load_lds(
        (const __attribute__((address_space(1))) unsigned int*)g,
        (__attribute__((address_space(3))) unsigned int*)l, 16, 0, 0);
}

#define XS    68            // LDS ci-stride in ushorts (136B -> 2-way bank alias, free)
#define WTAP  (128 * XS)    // 8704 ushorts / 17408 B per tap (padded, matches LDS layout)
#define NXP   340           // 10*34 halo pixels

// -------- weight pre-transform: OIHW f32 -> padded [tap][co][XS] bf16 --------
// Output layout is byte-identical to the conv kernel's LDS weight buffer, so
// staging is a straight contiguous global_load_lds copy (wave-uniform dest rule).
__global__ void __launch_bounds__(256) wxform(const float* __restrict__ W,
                                              unsigned short* __restrict__ wpad) {
    int o = blockIdx.x * 256 + threadIdx.x;        // 9*128*68 = 78336
    if (o < 9 * 128 * XS) {
        int tap = o / (128 * XS);
        int r   = o % (128 * XS);
        int co  = r / XS;
        int ci  = r % XS;
        unsigned short v = 0;
        if (ci < 64) v = f2bf(W[co * 576 + ci * 9 + tap]);   // W[co][ci][kh][kw]
        wpad[o] = v;
    }
}

struct SmemT {
    unsigned short x[NXP * XS];      // 46240 B : halo [px][ci] bf16
    unsigned short w[2][128 * XS];   // 34816 B : double-buffered tap weights
};                                   // total 81056 B -> 2 blocks/CU

// -------- fused conv3x3 + bias + avgpool2 + sigmoid + per-image sum --------
// Block: 8 rows x 32 cols x 128 co. Wave v owns rows {2v, 2v+1} (one pool row).
__global__ void __launch_bounds__(256, 2)
conv_fused(const float* __restrict__ x,
           const unsigned short* __restrict__ wpad,
           const float* __restrict__ bias,
           float* __restrict__ out)
{
    __shared__ __align__(16) SmemT sm;
    __shared__ float red[4];

    const int tid  = threadIdx.x;
    const int wave = tid >> 6;
    const int lane = tid & 63;
    const int lq   = lane >> 4;
    const int lm   = lane & 15;

    const int ct = blockIdx.x;        // 0..3   col tile (32 wide)
    const int rt = blockIdx.y;        // 0..15  row tile (8 tall)
    const int n  = blockIdx.z;        // 0..63  image

    const int h0 = rt * 8;
    const int w0 = ct * 32;
    const float* xn = x + (size_t)n * (64u * 128u * 128u);

    // ---- issue async prefetch of tap-0 weights (17 x 1KB chunks, round-robin waves)
    for (int c = wave; c < 17; c += 4)
        gl2lds16(wpad + c * 512 + lane * 8, &sm.w[0][c * 512]);

    // ---- stage x halo: 64ci x 10h x 34w -> LDS [px][ci] bf16 (overlaps prefetch)
    for (int it = 0; it < 11; ++it) {
        int t = tid + it * 256;
        if (t < NXP * 8) {                     // 2720 tasks
            int px = t % NXP;                  // consecutive lanes -> consecutive w
            int g  = t / NXP;                  // ci-group (8 ci)
            int hh = px / 34, ww = px % 34;
            int h = h0 + hh, w = w0 + ww;
            bool ok = (h < 128) && (w < 128);
            const float* src = xn + (size_t)(g * 8) * 16384 + h * 128 + w;
            us8 v;
            #pragma unroll
            for (int j = 0; j < 8; ++j) {
                float f = ok ? src[j * 16384] : 0.0f;
                v[j] = f2bf(f);
            }
            *(us8*)&sm.x[px * XS + g * 8] = v;
        }
    }

    // bias preload (co = nt*16 + lm)
    float bv[8];
    #pragma unroll
    for (int nt = 0; nt < 8; ++nt) bv[nt] = bias[nt * 16 + lm];

    f32x4 acc[4][8];                  // [rl*2+ch][nt] : 128 VGPRs
    #pragma unroll
    for (int mt = 0; mt < 4; ++mt)
        #pragma unroll
        for (int nt = 0; nt < 8; ++nt)
            acc[mt][nt] = (f32x4){0.f, 0.f, 0.f, 0.f};

    __syncthreads();   // drains x ds_writes + tap0 global_load_lds

    // ---- K loop: 9 taps, weights double-buffered, ONE barrier per tap ----
    for (int tap = 0; tap < 9; ++tap) {
        const int cur = tap & 1;
        if (tap < 8) {                // prefetch tap+1 into other buffer
            const unsigned short* wt = wpad + (tap + 1) * WTAP;
            for (int c = wave; c < 17; c += 4)
                gl2lds16(wt + c * 512 + lane * 8, &sm.w[cur ^ 1][c * 512]);
        }
        const int kh = tap / 3, kw = tap - kh * 3;

        // A frags: A[m=lm][k=lq*8+j], m = pixel col
        bf16x8 a[2][2][2];            // [rl][ch][kc]
        #pragma unroll
        for (int rl = 0; rl < 2; ++rl)
            #pragma unroll
            for (int ch = 0; ch < 2; ++ch)
                #pragma unroll
                for (int kc = 0; kc < 2; ++kc) {
                    int px = (2 * wave + rl + kh) * 34 + ch * 16 + lm + kw;
                    a[rl][ch][kc] = *(const bf16x8*)&sm.x[px * XS + kc * 32 + lq * 8];
                }
        #pragma unroll
        for (int nt = 0; nt < 8; ++nt) {
            #pragma unroll
            for (int kc = 0; kc < 2; ++kc) {
                bf16x8 b = *(const bf16x8*)&sm.w[cur][(nt * 16 + lm) * XS + kc * 32 + lq * 8];
                #pragma unroll
                for (int rl = 0; rl < 2; ++rl)
                    #pragma unroll
                    for (int ch = 0; ch < 2; ++ch)
                        acc[rl * 2 + ch][nt] = __builtin_amdgcn_mfma_f32_16x16x32_bf16(
                            a[rl][ch][kc], b, acc[rl * 2 + ch][nt], 0, 0, 0);
            }
        }
        __syncthreads();  // all waves done with w[cur]; drains prefetch into w[cur^1]
    }

    // ---- in-register epilogue: D rows rl=0/1 are a vertical pool pair; the 4
    // regs rr=0..3 (pixel cols lq*4+rr) give two horizontal pool pairs. ----
    float part = 0.0f;
    const int ph = rt * 4 + wave;                 // pool row (wave-uniform)
    if (ph < 63) {
        #pragma unroll
        for (int ch = 0; ch < 2; ++ch) {
            const int pwb = ct * 16 + ch * 8 + lq * 2;
            #pragma unroll
            for (int nt = 0; nt < 8; ++nt) {
                f32x4 s = acc[ch][nt] + acc[2 + ch][nt];   // vertical pool sum
                float p0 = s[0] + s[1];                    // cols (0,1) of quad
                float p1 = s[2] + s[3];                    // cols (2,3)
                float bb = bv[nt];
                if (pwb < 63) {
                    float v = 0.25f * p0 + bb;
                    part += 1.0f / (1.0f + __expf(-v));
                }
                if (pwb + 1 < 63) {
                    float v = 0.25f * p1 + bb;
                    part += 1.0f / (1.0f + __expf(-v));
                }
            }
        }
    }

    // ---- block reduce -> one atomicAdd per block ----
    #pragma unroll
    for (int off = 32; off > 0; off >>= 1)
        part += __shfl_down(part, off, 64);
    if (lane == 0) red[wave] = part;
    __syncthreads();
    if (tid == 0) atomicAdd(&out[n], red[0] + red[1] + red[2] + red[3]);
}

extern "C" void kernel_launch(void* const* d_in, const int* in_sizes, int n_in,
                              void* d_out, int out_size, void* d_ws, size_t ws_size,
                              hipStream_t stream) {
    const float* x = (const float*)d_in[0];
    const float* W = (const float*)d_in[1];
    const float* b = (const float*)d_in[2];
    float* out = (float*)d_out;
    unsigned short* wpad = (unsigned short*)d_ws;   // 156672 B used

    hipMemsetAsync(d_out, 0, 64 * sizeof(float), stream);
    wxform<<<(9 * 128 * XS + 255) / 256, 256, 0, stream>>>(W, wpad);
    conv_fused<<<dim3(4, 16, 64), 256, 0, stream>>>(x, wpad, b, out);
}